// Round 33
// baseline (297.985 us; speedup 1.0000x reference)
//
#include <hip/hip_runtime.h>
#include <math.h>

#define SEQ 2048
#define DMODEL 1024
#define NHEADS 16
#define HDIM 64
#define BATCH 2
#define MROWS (BATCH*SEQ)    // 4096
#define BHTOT (BATCH*NHEADS) // 32
#define NKT (SEQ/64)         // 32 k-tiles per head

typedef __attribute__((ext_vector_type(8))) short bf16x8_t;
typedef __attribute__((ext_vector_type(4))) float f32x4_t;
typedef __attribute__((ext_vector_type(16))) float f32x16_t;
typedef unsigned short u16;
typedef unsigned int u32;

__device__ __forceinline__ u16 f2bf(float x) {
    u32 u = __float_as_uint(x);
    return (u16)((u + 0x7FFFu + ((u >> 16) & 1u)) >> 16);
}
__device__ __forceinline__ float bf2f(u16 h) {
    return __uint_as_float(((u32)h) << 16);
}
// XOR swizzle (T2 / m201 pattern): permute 16B slots within a 128B row
__device__ __forceinline__ int swz(int row, int colbyte) {
    return colbyte ^ ((row & 7) << 4);
}
// v_cvt_pk_bf16_f32: dst.lo16 = bf16(a), dst.hi16 = bf16(b)
__device__ __forceinline__ u32 cvtpk(float a, float b) {
    u32 r;
    asm("v_cvt_pk_bf16_f32 %0, %1, %2" : "=v"(r) : "v"(a), "v"(b));
    return r;
}
// v_permlane32_swap_b32: a.lanes[32:63] <-> b.lanes[0:31]
__device__ __forceinline__ void plswap(u32& a, u32& b) {
    asm("v_permlane32_swap_b32 %0, %1" : "+v"(a), "+v"(b));
}
__device__ __forceinline__ float bfhi_lo(u32 w) { return __uint_as_float(w << 16); }
__device__ __forceinline__ float bfhi_hi(u32 w) { return __uint_as_float(w & 0xFFFF0000u); }

// stage helper: load 8 fp32, split to hi/lo bf16 uint4 pair
__device__ __forceinline__ void splitldg(const float* p, uint4& h, uint4& l) {
    float4 a0 = *(const float4*)p;
    float4 a1 = *(const float4*)(p + 4);
    u32 h0 = cvtpk(a0.x, a0.y), h1 = cvtpk(a0.z, a0.w);
    u32 h2 = cvtpk(a1.x, a1.y), h3 = cvtpk(a1.z, a1.w);
    u32 l0 = cvtpk(a0.x - bfhi_lo(h0), a0.y - bfhi_hi(h0));
    u32 l1 = cvtpk(a0.z - bfhi_lo(h1), a0.w - bfhi_hi(h1));
    u32 l2 = cvtpk(a1.x - bfhi_lo(h2), a1.y - bfhi_hi(h2));
    u32 l3 = cvtpk(a1.z - bfhi_lo(h3), a1.w - bfhi_hi(h3));
    h = (uint4){h0, h1, h2, h3};
    l = (uint4){l0, l1, l2, l3};
}

// ---------------------------------------------------------------------------
// Fused Q/K/V projection GEMM, 64x128 tile: grid 8 x 64 x 3 = 1536 blocks
// (~5/CU co-resident, LDS 30 KB). A and W both fp32, split to hi/lo
// in-register during staging (3-term bf16 MFMA). 4 waves; each owns a
// 64x32 column slice.
// Staging thread map r=tid&63 (row-fast): LDS write bank starts 20*r mod 32
// -> uniform 2/bank per quarter-wave, matching the conflict-free read
// pattern (old r=tid>>2 map had 3-way write collisions = 1.9e7/dispatch).
// z=0,1: head layout [bh][2048 s][64 d]; z=2: V-transposed [bh][64 d][2048 s]
// + fused per-tile V column sums (complete per block, no atomics).
// ---------------------------------------------------------------------------
__global__ __launch_bounds__(256)
void gemm_qkv(const float* __restrict__ Qf, const float* __restrict__ Kf,
              const float* __restrict__ Vf,
              const float* __restrict__ Wqf, const float* __restrict__ Wkf,
              const float* __restrict__ Wvf,
              const float* __restrict__ bq, const float* __restrict__ bk,
              const float* __restrict__ bv,
              u16* __restrict__ q_hi, u16* __restrict__ q_lo,
              u16* __restrict__ k_hi, u16* __restrict__ k_lo,
              u16* __restrict__ vt_hi, u16* __restrict__ vt_lo,
              float* __restrict__ cs) {
    const int K = 1024, N = 1024;
    __shared__ u16 As_h[64 * 40];
    __shared__ u16 As_l[64 * 40];
    __shared__ u16 Ws_h[128 * 40];
    __shared__ u16 Ws_l[128 * 40];   // 30 KB total

    const int z = blockIdx.z;
    const float* Afp = (z == 0) ? Qf : (z == 1) ? Kf : Vf;
    const float* Wfp = (z == 0) ? Wqf : (z == 1) ? Wkf : Wvf;
    const float* bias = (z == 0) ? bq : (z == 1) ? bk : bv;
    const float oscale = (z == 0) ? 0.125f : 1.f;

    const int tid = threadIdx.x;
    const int lane = tid & 63, w = tid >> 6;     // w = wave = W column slice
    const int m0 = blockIdx.y * 64, n0 = blockIdx.x * 128;
    const int rb = lane & 15, ko = (lane >> 4) * 8;
    const int sr = tid & 63, sq = tid >> 6;      // staging map: row-fast

    f32x4_t acc[4][2];
    #pragma unroll
    for (int i = 0; i < 4; ++i)
        #pragma unroll
        for (int j = 0; j < 2; ++j)
            acc[i][j] = (f32x4_t){0.f, 0.f, 0.f, 0.f};

    for (int k0 = 0; k0 < K; k0 += 32) {
        {   // stage A-tile (fp32 -> split): 64 rows x 32 halves
            size_t ga = (size_t)(m0 + sr) * K + k0 + sq * 8;
            int la = sr * 40 + sq * 8;
            uint4 h, l;
            splitldg(Afp + ga, h, l);
            *(uint4*)&As_h[la] = h;
            *(uint4*)&As_l[la] = l;
        }
        #pragma unroll
        for (int s = 0; s < 2; ++s) {   // stage W-tile (fp32 -> split)
            int r = sr + s * 64;
            size_t gw = (size_t)(n0 + r) * K + k0 + sq * 8;
            int la = r * 40 + sq * 8;
            uint4 h, l;
            splitldg(Wfp + gw, h, l);
            *(uint4*)&Ws_h[la] = h;
            *(uint4*)&Ws_l[la] = l;
        }
        __syncthreads();

        bf16x8_t ah[4], al[4];
        #pragma unroll
        for (int i = 0; i < 4; ++i) {
            int ra = i * 16 + rb;
            ah[i] = *(const bf16x8_t*)&As_h[ra * 40 + ko];
            al[i] = *(const bf16x8_t*)&As_l[ra * 40 + ko];
        }
        #pragma unroll
        for (int j = 0; j < 2; ++j) {
            int rw = w * 32 + j * 16 + rb;
            bf16x8_t wh = *(const bf16x8_t*)&Ws_h[rw * 40 + ko];
            bf16x8_t wl = *(const bf16x8_t*)&Ws_l[rw * 40 + ko];
            #pragma unroll
            for (int i = 0; i < 4; ++i) {
                acc[i][j] = __builtin_amdgcn_mfma_f32_16x16x32_bf16(ah[i], wh, acc[i][j], 0, 0, 0);
                acc[i][j] = __builtin_amdgcn_mfma_f32_16x16x32_bf16(ah[i], wl, acc[i][j], 0, 0, 0);
                acc[i][j] = __builtin_amdgcn_mfma_f32_16x16x32_bf16(al[i], wh, acc[i][j], 0, 0, 0);
            }
        }
        __syncthreads();
    }

    if (z == 2) {
        // V: transposed head layout, 4 consecutive s per frag -> ushort4 store
        #pragma unroll
        for (int i = 0; i < 4; ++i)
            #pragma unroll
            for (int j = 0; j < 2; ++j) {
                int mb = m0 + i * 16 + (lane >> 4) * 4;
                int n = n0 + w * 32 + j * 16 + rb;
                int bb = mb >> 11, s0 = mb & (SEQ - 1);
                int hh = n >> 6, dd = n & 63;
                size_t idx = (((size_t)(bb * 16 + hh) * 64) + dd) * SEQ + s0;
                float bn = bias[n];
                ushort4 h4, l4;
                float v0 = acc[i][j][0] + bn;
                float v1 = acc[i][j][1] + bn;
                float v2 = acc[i][j][2] + bn;
                float v3 = acc[i][j][3] + bn;
                h4.x = f2bf(v0); l4.x = f2bf(v0 - bf2f(h4.x));
                h4.y = f2bf(v1); l4.y = f2bf(v1 - bf2f(h4.y));
                h4.z = f2bf(v2); l4.z = f2bf(v2 - bf2f(h4.z));
                h4.w = f2bf(v3); l4.w = f2bf(v3 - bf2f(h4.w));
                *(ushort4*)&vt_hi[idx] = h4;
                *(ushort4*)&vt_lo[idx] = l4;
            }
        // fused per-tile V column sums: complete within this block
        {
            int kt = (m0 & (SEQ - 1)) >> 6;
            int bb = m0 >> 11;
            #pragma unroll
            for (int j = 0; j < 2; ++j) {
                int n = n0 + w * 32 + j * 16 + rb;
                float part = 0.f;
                #pragma unroll
                for (int i = 0; i < 4; ++i)
                    #pragma unroll
                    for (int r = 0; r < 4; ++r)
                        part += acc[i][j][r];
                part += __shfl_xor(part, 16);
                part += __shfl_xor(part, 32);   // sum over 4 lane-groups = 64 rows
                if ((lane >> 4) == 0) {
                    int hh = n >> 6, dd = n & 63;
                    cs[(((size_t)(bb * 16 + hh)) * NKT + kt) * 64 + dd] =
                        part + 64.f * bias[n];
                }
            }
        }
    } else {
        u16* Ch = (z == 0) ? q_hi : k_hi;
        u16* Cl = (z == 0) ? q_lo : k_lo;
        #pragma unroll
        for (int i = 0; i < 4; ++i)
            #pragma unroll
            for (int j = 0; j < 2; ++j)
                #pragma unroll
                for (int r = 0; r < 4; ++r) {
                    int m = m0 + i * 16 + (lane >> 4) * 4 + r;
                    int n = n0 + w * 32 + j * 16 + rb;
                    float v = (acc[i][j][r] + bias[n]) * oscale;
                    int bb = m >> 11, s = m & (SEQ - 1);
                    int hh = n >> 6, dd = n & 63;
                    size_t idx = (((size_t)(bb * 16 + hh) * SEQ) + s) * 64 + dd;
                    u16 t = f2bf(v);
                    Ch[idx] = t;
                    Cl[idx] = f2bf(v - bf2f(t));
                }
    }
}

// ---------------------------------------------------------------------------
// Output projection GEMM, 64x128 tile: 512 blocks = 2/CU co-resident.
// C = A @ W^T + bias (fp32 C). A pre-split (attn epilogue); W fp32, split
// in-register during staging. Same row-fast staging map as gemm_qkv.
// ---------------------------------------------------------------------------
__global__ __launch_bounds__(256)
void gemm_out(const u16* __restrict__ Ahi, const u16* __restrict__ Alo,
              const float* __restrict__ Wfp,
              const float* __restrict__ bias, float* __restrict__ C) {
    const int K = 1024, N = 1024;
    __shared__ u16 As_h[64 * 40];
    __shared__ u16 As_l[64 * 40];
    __shared__ u16 Ws_h[128 * 40];
    __shared__ u16 Ws_l[128 * 40];   // 30 KB total

    const int tid = threadIdx.x;
    const int lane = tid & 63, w = tid >> 6;     // w = wave = column slice
    const int m0 = blockIdx.y * 64, n0 = blockIdx.x * 128;
    const int rb = lane & 15, ko = (lane >> 4) * 8;
    const int sr = tid & 63, sq = tid >> 6;      // staging map: row-fast

    f32x4_t acc[4][2];
    #pragma unroll
    for (int i = 0; i < 4; ++i)
        #pragma unroll
        for (int j = 0; j < 2; ++j)
            acc[i][j] = (f32x4_t){0.f, 0.f, 0.f, 0.f};

    for (int k0 = 0; k0 < K; k0 += 32) {
        {   // stage A-tile: 64 rows x 32 halves = 1 uint4/thread (pre-split)
            size_t ga = (size_t)(m0 + sr) * K + k0 + sq * 8;
            int la = sr * 40 + sq * 8;
            *(uint4*)&As_h[la] = *(const uint4*)&Ahi[ga];
            *(uint4*)&As_l[la] = *(const uint4*)&Alo[ga];
        }
        #pragma unroll
        for (int s = 0; s < 2; ++s) {   // stage W-tile (fp32 -> split)
            int r = sr + s * 64;
            size_t gw = (size_t)(n0 + r) * K + k0 + sq * 8;
            int la = r * 40 + sq * 8;
            uint4 h, l;
            splitldg(Wfp + gw, h, l);
            *(uint4*)&Ws_h[la] = h;
            *(uint4*)&Ws_l[la] = l;
        }
        __syncthreads();

        bf16x8_t ah[4], al[4];
        #pragma unroll
        for (int i = 0; i < 4; ++i) {
            int ra = i * 16 + rb;
            ah[i] = *(const bf16x8_t*)&As_h[ra * 40 + ko];
            al[i] = *(const bf16x8_t*)&As_l[ra * 40 + ko];
        }
        #pragma unroll
        for (int j = 0; j < 2; ++j) {
            int rw = w * 32 + j * 16 + rb;
            bf16x8_t wh = *(const bf16x8_t*)&Ws_h[rw * 40 + ko];
            bf16x8_t wl = *(const bf16x8_t*)&Ws_l[rw * 40 + ko];
            #pragma unroll
            for (int i = 0; i < 4; ++i) {
                acc[i][j] = __builtin_amdgcn_mfma_f32_16x16x32_bf16(ah[i], wh, acc[i][j], 0, 0, 0);
                acc[i][j] = __builtin_amdgcn_mfma_f32_16x16x32_bf16(ah[i], wl, acc[i][j], 0, 0, 0);
                acc[i][j] = __builtin_amdgcn_mfma_f32_16x16x32_bf16(al[i], wh, acc[i][j], 0, 0, 0);
            }
        }
        __syncthreads();
    }

    #pragma unroll
    for (int i = 0; i < 4; ++i)
        #pragma unroll
        for (int j = 0; j < 2; ++j)
            #pragma unroll
            for (int r = 0; r < 4; ++r) {
                int m = m0 + i * 16 + (lane >> 4) * 4 + r;
                int n = n0 + w * 32 + j * 16 + rb;
                C[(size_t)m * N + n] = acc[i][j][r] + bias[n];
            }
}

// ---------------------------------------------------------------------------
// MFMA flash attention on 32x32x16 frags, P entirely in registers.
// (r14/r29-measured 92 us structure.) Block = 4 waves x 32 q-rows.
// S^T = mfma(K, Q): q lane-local -> softmax via one shfl_xor(32); P relayout
// to PV B-operand via cvt_pk_bf16 + v_permlane32_swap. K/V in LDS (32 KB),
// XOR-swizzled; 2 barriers/tile. Fully-masked suffix handled analytically;
// the needed suffix-of-colsums is computed IN-BLOCK from cs (replaces the
// separate suffix_scan kernel). q pre-scaled by 0.125 in its projection.
// ---------------------------------------------------------------------------
__global__ __launch_bounds__(256)
void attn_mfma(const u16* __restrict__ qh_g, const u16* __restrict__ ql_g,
               const u16* __restrict__ kh_g, const u16* __restrict__ kl_g,
               const u16* __restrict__ vth_g, const u16* __restrict__ vtl_g,
               const float* __restrict__ cs,
               u16* __restrict__ ahi, u16* __restrict__ alo) {
    __shared__ alignas(16) u16 Kh[4096], Kl[4096];
    __shared__ alignas(16) u16 Vh[4096], Vl[4096];   // 32 KB total

    const int tid = threadIdx.x;
    const int lane = tid & 63, w = tid >> 6;
    const int q31 = lane & 31, g2 = lane >> 5;
    const int sidx = blockIdx.x >> 5;        // 0..15 dispatch slot
    const int stripe = (sidx < 8) ? (15 - sidx) : (sidx - 8);  // balanced pairing
    const int bh = blockIdx.x & 31;
    const int b = bh >> 4, h = bh & 15;
    const int qb0 = stripe << 7;
    const int dt_w = 2 * stripe + (w >> 1);  // this wave's diagonal tile
    const int nt_blk = 2 * stripe + 2;
    const int qrow = qb0 + w * 32 + q31;     // this lane's q (global in-head)

    // Q fragments (B-operand): col=q31, k(d) = 16*ks + 8*g2 + i
    bf16x8_t qfh[4], qfl[4];
    {
        const u16* qp = qh_g + ((size_t)bh * SEQ + qrow) * 64;
        const u16* qp2 = ql_g + ((size_t)bh * SEQ + qrow) * 64;
        #pragma unroll
        for (int ks = 0; ks < 4; ++ks) {
            qfh[ks] = *(const bf16x8_t*)(qp + ks * 16 + g2 * 8);
            qfl[ks] = *(const bf16x8_t*)(qp2 + ks * 16 + g2 * 8);
        }
    }

    f32x16_t o[2];
    #pragma unroll
    for (int dt = 0; dt < 2; ++dt)
        #pragma unroll
        for (int r = 0; r < 16; ++r) o[dt][r] = 0.f;
    float mrow = -1e30f, lrow = 0.f;

    const u16* khb = kh_g + (size_t)bh * SEQ * 64;
    const u16* klb = kl_g + (size_t)bh * SEQ * 64;
    const u16* vhb = vth_g + (size_t)bh * 64 * SEQ;
    const u16* vlb = vtl_g + (size_t)bh * 64 * SEQ;

    for (int kt = 0; kt < nt_blk; ++kt) {
        if (kt) __syncthreads();   // prior-tile LDS reads done before restage
        #pragma unroll
        for (int s = 0; s < 2; ++s) {
            int gg = tid + s * 256;          // 0..511
            int row = gg >> 3, dg = gg & 7;
            int off = row * 128 + swz(row, dg * 16);
            *(uint4*)((char*)Kh + off) = *(const uint4*)(khb + (size_t)(kt * 64 + row) * 64 + dg * 8);
            *(uint4*)((char*)Kl + off) = *(const uint4*)(klb + (size_t)(kt * 64 + row) * 64 + dg * 8);
            *(uint4*)((char*)Vh + off) = *(const uint4*)(vhb + (size_t)row * SEQ + kt * 64 + dg * 8);
            *(uint4*)((char*)Vl + off) = *(const uint4*)(vlb + (size_t)row * SEQ + kt * 64 + dg * 8);
        }
        __syncthreads();           // staging visible
        if (kt > dt_w) continue;   // wave-uniform; barriers stay aligned

        // ---- QK^T: st[jt] = S^T frag (rows j, cols q) ----
        f32x16_t st[2];
        #pragma unroll
        for (int jt = 0; jt < 2; ++jt)
            #pragma unroll
            for (int r = 0; r < 16; ++r) st[jt][r] = 0.f;
        #pragma unroll
        for (int ks = 0; ks < 4; ++ks)
            #pragma unroll
            for (int jt = 0; jt < 2; ++jt) {
                int row = jt * 32 + q31;
                int off = row * 128 + swz(row, ks * 32 + g2 * 16);
                bf16x8_t kh8 = *(const bf16x8_t*)((char*)Kh + off);
                bf16x8_t kl8 = *(const bf16x8_t*)((char*)Kl + off);
                st[jt] = __builtin_amdgcn_mfma_f32_32x32x16_bf16(kh8, qfh[ks], st[jt], 0, 0, 0);
                st[jt] = __builtin_amdgcn_mfma_f32_32x32x16_bf16(kh8, qfl[ks], st[jt], 0, 0, 0);
                st[jt] = __builtin_amdgcn_mfma_f32_32x32x16_bf16(kl8, qfh[ks], st[jt], 0, 0, 0);
            }

        // causal mask on the diagonal tile (reference semantics: -1e-9)
        if (kt == dt_w) {
            #pragma unroll
            for (int jt = 0; jt < 2; ++jt)
                #pragma unroll
                for (int r = 0; r < 16; ++r) {
                    int j = kt * 64 + jt * 32 + (r & 3) + 8 * (r >> 2) + 4 * g2;
                    if (j > qrow) st[jt][r] = -1e-9f;
                }
        }

        // ---- online softmax: q is lane-local; partner lane^32 has the
        //      complementary j-subset -> one shfl_xor each for max & sum ----
        float mx = -1e30f;
        #pragma unroll
        for (int jt = 0; jt < 2; ++jt)
            #pragma unroll
            for (int r = 0; r < 16; ++r) mx = fmaxf(mx, st[jt][r]);
        mx = fmaxf(mx, __shfl_xor(mx, 32));
        float nm = fmaxf(mrow, mx);
        float alpha = __expf(mrow - nm);
        mrow = nm;
        float rs = 0.f;
        #pragma unroll
        for (int jt = 0; jt < 2; ++jt)
            #pragma unroll
            for (int r = 0; r < 16; ++r) {
                float p = __expf(st[jt][r] - nm);
                st[jt][r] = p;
                rs += p;
            }
        rs += __shfl_xor(rs, 32);
        lrow = lrow * alpha + rs;
        #pragma unroll
        for (int dt = 0; dt < 2; ++dt)
            #pragma unroll
            for (int r = 0; r < 16; ++r) o[dt][r] *= alpha;

        // ---- pack P to PV B-frags in-register (cvt_pk + permlane32_swap) ----
        bf16x8_t pbh[4], pbl[4];
        #pragma unroll
        for (int jt = 0; jt < 2; ++jt) {
            u32 hq[8], lq[8];
            #pragma unroll
            for (int p2 = 0; p2 < 8; ++p2) {
                float s0 = st[jt][p2 * 2], s1 = st[jt][p2 * 2 + 1];
                u32 hk = cvtpk(s0, s1);
                hq[p2] = hk;
                float l0 = s0 - __uint_as_float(hk << 16);
                float l1 = s1 - __uint_as_float(hk & 0xFFFF0000u);
                lq[p2] = cvtpk(l0, l1);
            }
            // halves: r0-7 -> ks=2jt, r8-15 -> ks=2jt+1
            plswap(hq[0], hq[2]); plswap(hq[1], hq[3]);
            plswap(hq[4], hq[6]); plswap(hq[5], hq[7]);
            plswap(lq[0], lq[2]); plswap(lq[1], lq[3]);
            plswap(lq[4], lq[6]); plswap(lq[5], lq[7]);
            uint4 t;
            t = (uint4){hq[0], hq[1], hq[2], hq[3]};
            pbh[2 * jt] = *(bf16x8_t*)&t;
            t = (uint4){hq[4], hq[5], hq[6], hq[7]};
            pbh[2 * jt + 1] = *(bf16x8_t*)&t;
            t = (uint4){lq[0], lq[1], lq[2], lq[3]};
            pbl[2 * jt] = *(bf16x8_t*)&t;
            t = (uint4){lq[4], lq[5], lq[6], lq[7]};
            pbl[2 * jt + 1] = *(bf16x8_t*)&t;
        }

        // ---- PV: O^T[dt] += V^T frag x P frag ----
        #pragma unroll
        for (int ks = 0; ks < 4; ++ks)
            #pragma unroll
            for (int dt = 0; dt < 2; ++dt) {
                int row = dt * 32 + q31;
                int off = row * 128 + swz(row, ks * 32 + g2 * 16);
                bf16x8_t vh8 = *(const bf16x8_t*)((char*)Vh + off);
                bf16x8_t vl8 = *(const bf16x8_t*)((char*)Vl + off);
                o[dt] = __builtin_amdgcn_mfma_f32_32x32x16_bf16(vh8, pbh[ks], o[dt], 0, 0, 0);
                o[dt] = __builtin_amdgcn_mfma_f32_32x32x16_bf16(vh8, pbl[ks], o[dt], 0, 0, 0);
                o[dt] = __builtin_amdgcn_mfma_f32_32x32x16_bf16(vl8, pbh[ks], o[dt], 0, 0, 0);
            }
    }

    // ---- in-block suffix-of-colsums (replaces suffix_scan kernel) ----
    // Shared part S2[d] = sum_{kt >= 2*stripe+2} cs[bh][kt][d]; waves 0,1
    // (diag one tile earlier) additionally add cs[bh][2*stripe+1][d].
    __syncthreads();                          // all waves done with K/V LDS
    float* sred = (float*)Kh;                 // reuse dead K region (8 KB)
    const int base_t = 2 * stripe + 2;
    {
        int d = tid & 63, grp = tid >> 6;     // 4 strided partial groups
        float s = 0.f;
        for (int t2 = base_t + grp; t2 < NKT; t2 += 4)
            s += cs[((size_t)bh * NKT + t2) * 64 + d];
        sred[grp * 64 + d] = s;
    }
    __syncthreads();
    if (tid < 64)
        sred[256 + tid] = (sred[tid] + sred[64 + tid]) +
                          (sred[128 + tid] + sred[192 + tid]);
    __syncthreads();

    // fully-masked suffix tiles: analytic e * suffix-colsum(V)
    const int nt_w = dt_w + 1;
    const int nfull = NKT - nt_w;
    if (nfull > 0) {
        float mm = fmaxf(mrow, -1e-9f);
        float al2 = __expf(mrow - mm);
        float ee = __expf(-1e-9f - mm);
        lrow = lrow * al2 + ee * (64.f * (float)nfull);
        const bool extra = (nt_w < base_t);   // waves 0,1: add one more tile
        const float* csrow = cs + ((size_t)bh * NKT + nt_w) * 64;
        #pragma unroll
        for (int dt = 0; dt < 2; ++dt)
            #pragma unroll
            for (int qq = 0; qq < 4; ++qq) {
                int d0 = dt * 32 + qq * 8 + g2 * 4;
                float4 sf = *(const float4*)&sred[256 + d0];
                if (extra) {
                    float4 c4 = *(const float4*)(csrow + d0);
                    sf.x += c4.x; sf.y += c4.y; sf.z += c4.z; sf.w += c4.w;
                }
                o[dt][qq * 4 + 0] = o[dt][qq * 4 + 0] * al2 + ee * sf.x;
                o[dt][qq * 4 + 1] = o[dt][qq * 4 + 1] * al2 + ee * sf.y;
                o[dt][qq * 4 + 2] = o[dt][qq * 4 + 2] * al2 + ee * sf.z;
                o[dt][qq * 4 + 3] = o[dt][qq * 4 + 3] * al2 + ee * sf.w;
            }
    }

    // epilogue: normalize + write bf16 hi/lo in [B*S][DMODEL]
    float inv = 1.f / lrow;
    size_t rowg = (size_t)b * SEQ + qrow;
    #pragma unroll
    for (int dt = 0; dt < 2; ++dt)
        #pragma unroll
        for (int qq = 0; qq < 4; ++qq) {
            int d0 = dt * 32 + qq * 8 + g2 * 4;
            ushort4 h4, l4;
            float v0 = o[dt][qq * 4 + 0] * inv;
            float v1 = o[dt][qq * 4 + 1] * inv;
            float v2 = o[dt][qq * 4 + 2] * inv;
            float v3 = o[dt][qq * 4 + 3] * inv;
            h4.x = f2bf(v0); l4.x = f2bf(v0 - bf2f(h4.x));
            h4.y = f2bf(v1); l4.y = f2bf(v1 - bf2f(h4.y));
            h4.z = f2bf(v2); l4.z = f2bf(v2 - bf2f(h4.z));
            h4.w = f2bf(v3); l4.w = f2bf(v3 - bf2f(h4.w));
            size_t col = (size_t)h * 64 + d0;
            *(ushort4*)&ahi[rowg * DMODEL + col] = h4;
            *(ushort4*)&alo[rowg * DMODEL + col] = l4;
        }
}

// ---------------------------------------------------------------------------
extern "C" void kernel_launch(void* const* d_in, const int* in_sizes, int n_in,
                              void* d_out, int out_size, void* d_ws, size_t ws_size,
                              hipStream_t stream) {
    const float* Q   = (const float*)d_in[0];
    const float* K   = (const float*)d_in[1];
    const float* V   = (const float*)d_in[2];
    // d_in[3] = mask (tril) — structure known, not read
    const float* Wq  = (const float*)d_in[4];
    const float* bq  = (const float*)d_in[5];
    const float* Wk  = (const float*)d_in[6];
    const float* bk  = (const float*)d_in[7];
    const float* Wv  = (const float*)d_in[8];
    const float* bv  = (const float*)d_in[9];
    const float* Wo  = (const float*)d_in[10];
    const float* bo  = (const float*)d_in[11];
    float* out = (float*)d_out;

    float* ws = (float*)d_ws;
    const size_t HEADSZ = (size_t)BHTOT * SEQ * HDIM;   // 4,194,304 elems
    float* cs_ws  = ws;                                  // 65536 f
    u16* base  = (u16*)(ws + 131072);
    u16* q_hi  = base;
    u16* q_lo  = base + HEADSZ;
    u16* k_hi  = base + 2 * HEADSZ;
    u16* k_lo  = base + 3 * HEADSZ;
    u16* vt_hi = base + 4 * HEADSZ;
    u16* vt_lo = base + 5 * HEADSZ;
    u16* in_hi = base + 6 * HEADSZ;   // attn output splits (O-GEMM input)
    u16* in_lo = base + 7 * HEADSZ;

    dim3 gblk(256);
    dim3 gout(DMODEL / 128, MROWS / 64);                 // 8 x 64 = 512 blocks
    dim3 gqkv(DMODEL / 128, MROWS / 64, 3);              // 8 x 64 x 3 = 1536 blocks

    // fused Q/K/V projections (A+W split in-staging; V colsums fused)
    gemm_qkv<<<gqkv, gblk, 0, stream>>>(Q, K, V, Wq, Wk, Wv, bq, bk, bv,
                                        q_hi, q_lo, k_hi, k_lo, vt_hi, vt_lo,
                                        cs_ws);

    // MFMA flash attention (suffix-of-colsums computed in-block from cs)
    attn_mfma<<<dim3(16 * BHTOT), gblk, 0, stream>>>(q_hi, q_lo, k_hi, k_lo,
                                                     vt_hi, vt_lo, cs_ws,
                                                     in_hi, in_lo);

    // output projection (64x128 tiles, 512 blocks = 2/CU; W split in-staging)
    gemm_out<<<gout, gblk, 0, stream>>>(in_hi, in_lo, Wo, bo, out);
}

// Round 34
// 225.160 us; speedup vs baseline: 1.3234x; 1.3234x over previous
//
#include <hip/hip_runtime.h>
#include <math.h>

#define SEQ 2048
#define DMODEL 1024
#define NHEADS 16
#define HDIM 64
#define BATCH 2
#define MROWS (BATCH*SEQ)    // 4096
#define BHTOT (BATCH*NHEADS) // 32
#define NKT (SEQ/64)         // 32 k-tiles per head

typedef __attribute__((ext_vector_type(8))) short bf16x8_t;
typedef __attribute__((ext_vector_type(4))) float f32x4_t;
typedef __attribute__((ext_vector_type(16))) float f32x16_t;
typedef unsigned short u16;
typedef unsigned int u32;

__device__ __forceinline__ u16 f2bf(float x) {
    u32 u = __float_as_uint(x);
    return (u16)((u + 0x7FFFu + ((u >> 16) & 1u)) >> 16);
}
__device__ __forceinline__ float bf2f(u16 h) {
    return __uint_as_float(((u32)h) << 16);
}
// XOR swizzle (T2 / m201 pattern): permute 16B slots within a 128B row
__device__ __forceinline__ int swz(int row, int colbyte) {
    return colbyte ^ ((row & 7) << 4);
}
// v_cvt_pk_bf16_f32: dst.lo16 = bf16(a), dst.hi16 = bf16(b)
__device__ __forceinline__ u32 cvtpk(float a, float b) {
    u32 r;
    asm("v_cvt_pk_bf16_f32 %0, %1, %2" : "=v"(r) : "v"(a), "v"(b));
    return r;
}
// v_permlane32_swap_b32: a.lanes[32:63] <-> b.lanes[0:31]
__device__ __forceinline__ void plswap(u32& a, u32& b) {
    asm("v_permlane32_swap_b32 %0, %1" : "+v"(a), "+v"(b));
}
__device__ __forceinline__ float bfhi_lo(u32 w) { return __uint_as_float(w << 16); }
__device__ __forceinline__ float bfhi_hi(u32 w) { return __uint_as_float(w & 0xFFFF0000u); }

// stage helper: load 8 fp32, split to hi/lo bf16 uint4 pair
__device__ __forceinline__ void splitldg(const float* p, uint4& h, uint4& l) {
    float4 a0 = *(const float4*)p;
    float4 a1 = *(const float4*)(p + 4);
    u32 h0 = cvtpk(a0.x, a0.y), h1 = cvtpk(a0.z, a0.w);
    u32 h2 = cvtpk(a1.x, a1.y), h3 = cvtpk(a1.z, a1.w);
    u32 l0 = cvtpk(a0.x - bfhi_lo(h0), a0.y - bfhi_hi(h0));
    u32 l1 = cvtpk(a0.z - bfhi_lo(h1), a0.w - bfhi_hi(h1));
    u32 l2 = cvtpk(a1.x - bfhi_lo(h2), a1.y - bfhi_hi(h2));
    u32 l3 = cvtpk(a1.z - bfhi_lo(h3), a1.w - bfhi_hi(h3));
    h = (uint4){h0, h1, h2, h3};
    l = (uint4){l0, l1, l2, l3};
}

// ---------------------------------------------------------------------------
// Fused Q/K/V projection GEMM, 64x128 tile: grid 8 x 64 x 3 = 1536 blocks
// (~5/CU co-resident, LDS 30 KB). A and W both fp32, split to hi/lo
// in-register during staging (3-term bf16 MFMA). 4 waves; each owns a
// 64x32 column slice. Staging map r=tid>>2,q=tid&3: 4-lane clusters cover
// 128B contiguous global (coalesced). NOTE r33: the 3-way LDS write-bank
// conflict of this map is accepted — the row-fast alternative fixes it but
// destroys coalescing (16x transactions, -60% measured).
// z=0,1: head layout [bh][2048 s][64 d]; z=2: V-transposed [bh][64 d][2048 s]
// + fused per-tile V column sums (complete per block, no atomics).
// ---------------------------------------------------------------------------
__global__ __launch_bounds__(256)
void gemm_qkv(const float* __restrict__ Qf, const float* __restrict__ Kf,
              const float* __restrict__ Vf,
              const float* __restrict__ Wqf, const float* __restrict__ Wkf,
              const float* __restrict__ Wvf,
              const float* __restrict__ bq, const float* __restrict__ bk,
              const float* __restrict__ bv,
              u16* __restrict__ q_hi, u16* __restrict__ q_lo,
              u16* __restrict__ k_hi, u16* __restrict__ k_lo,
              u16* __restrict__ vt_hi, u16* __restrict__ vt_lo,
              float* __restrict__ cs) {
    const int K = 1024, N = 1024;
    __shared__ u16 As_h[64 * 40];
    __shared__ u16 As_l[64 * 40];
    __shared__ u16 Ws_h[128 * 40];
    __shared__ u16 Ws_l[128 * 40];   // 30 KB total

    const int z = blockIdx.z;
    const float* Afp = (z == 0) ? Qf : (z == 1) ? Kf : Vf;
    const float* Wfp = (z == 0) ? Wqf : (z == 1) ? Wkf : Wvf;
    const float* bias = (z == 0) ? bq : (z == 1) ? bk : bv;
    const float oscale = (z == 0) ? 0.125f : 1.f;

    const int tid = threadIdx.x;
    const int lane = tid & 63, w = tid >> 6;     // w = wave = W column slice
    const int m0 = blockIdx.y * 64, n0 = blockIdx.x * 128;
    const int rb = lane & 15, ko = (lane >> 4) * 8;

    f32x4_t acc[4][2];
    #pragma unroll
    for (int i = 0; i < 4; ++i)
        #pragma unroll
        for (int j = 0; j < 2; ++j)
            acc[i][j] = (f32x4_t){0.f, 0.f, 0.f, 0.f};

    for (int k0 = 0; k0 < K; k0 += 32) {
        {   // stage A-tile (fp32 -> split): 64 rows x 32 halves
            int r = tid >> 2, q = tid & 3;
            size_t ga = (size_t)(m0 + r) * K + k0 + q * 8;
            int la = r * 40 + q * 8;
            uint4 h, l;
            splitldg(Afp + ga, h, l);
            *(uint4*)&As_h[la] = h;
            *(uint4*)&As_l[la] = l;
        }
        #pragma unroll
        for (int s = 0; s < 2; ++s) {   // stage W-tile (fp32 -> split)
            int c = tid + s * 256;
            int r = c >> 2, q = c & 3;
            size_t gw = (size_t)(n0 + r) * K + k0 + q * 8;
            int la = r * 40 + q * 8;
            uint4 h, l;
            splitldg(Wfp + gw, h, l);
            *(uint4*)&Ws_h[la] = h;
            *(uint4*)&Ws_l[la] = l;
        }
        __syncthreads();

        bf16x8_t ah[4], al[4];
        #pragma unroll
        for (int i = 0; i < 4; ++i) {
            int ra = i * 16 + rb;
            ah[i] = *(const bf16x8_t*)&As_h[ra * 40 + ko];
            al[i] = *(const bf16x8_t*)&As_l[ra * 40 + ko];
        }
        #pragma unroll
        for (int j = 0; j < 2; ++j) {
            int rw = w * 32 + j * 16 + rb;
            bf16x8_t wh = *(const bf16x8_t*)&Ws_h[rw * 40 + ko];
            bf16x8_t wl = *(const bf16x8_t*)&Ws_l[rw * 40 + ko];
            #pragma unroll
            for (int i = 0; i < 4; ++i) {
                acc[i][j] = __builtin_amdgcn_mfma_f32_16x16x32_bf16(ah[i], wh, acc[i][j], 0, 0, 0);
                acc[i][j] = __builtin_amdgcn_mfma_f32_16x16x32_bf16(ah[i], wl, acc[i][j], 0, 0, 0);
                acc[i][j] = __builtin_amdgcn_mfma_f32_16x16x32_bf16(al[i], wh, acc[i][j], 0, 0, 0);
            }
        }
        __syncthreads();
    }

    if (z == 2) {
        // V: transposed head layout, 4 consecutive s per frag -> ushort4 store
        #pragma unroll
        for (int i = 0; i < 4; ++i)
            #pragma unroll
            for (int j = 0; j < 2; ++j) {
                int mb = m0 + i * 16 + (lane >> 4) * 4;
                int n = n0 + w * 32 + j * 16 + rb;
                int bb = mb >> 11, s0 = mb & (SEQ - 1);
                int hh = n >> 6, dd = n & 63;
                size_t idx = (((size_t)(bb * 16 + hh) * 64) + dd) * SEQ + s0;
                float bn = bias[n];
                ushort4 h4, l4;
                float v0 = acc[i][j][0] + bn;
                float v1 = acc[i][j][1] + bn;
                float v2 = acc[i][j][2] + bn;
                float v3 = acc[i][j][3] + bn;
                h4.x = f2bf(v0); l4.x = f2bf(v0 - bf2f(h4.x));
                h4.y = f2bf(v1); l4.y = f2bf(v1 - bf2f(h4.y));
                h4.z = f2bf(v2); l4.z = f2bf(v2 - bf2f(h4.z));
                h4.w = f2bf(v3); l4.w = f2bf(v3 - bf2f(h4.w));
                *(ushort4*)&vt_hi[idx] = h4;
                *(ushort4*)&vt_lo[idx] = l4;
            }
        // fused per-tile V column sums: complete within this block
        {
            int kt = (m0 & (SEQ - 1)) >> 6;
            int bb = m0 >> 11;
            #pragma unroll
            for (int j = 0; j < 2; ++j) {
                int n = n0 + w * 32 + j * 16 + rb;
                float part = 0.f;
                #pragma unroll
                for (int i = 0; i < 4; ++i)
                    #pragma unroll
                    for (int r = 0; r < 4; ++r)
                        part += acc[i][j][r];
                part += __shfl_xor(part, 16);
                part += __shfl_xor(part, 32);   // sum over 4 lane-groups = 64 rows
                if ((lane >> 4) == 0) {
                    int hh = n >> 6, dd = n & 63;
                    cs[(((size_t)(bb * 16 + hh)) * NKT + kt) * 64 + dd] =
                        part + 64.f * bias[n];
                }
            }
        }
    } else {
        u16* Ch = (z == 0) ? q_hi : k_hi;
        u16* Cl = (z == 0) ? q_lo : k_lo;
        #pragma unroll
        for (int i = 0; i < 4; ++i)
            #pragma unroll
            for (int j = 0; j < 2; ++j)
                #pragma unroll
                for (int r = 0; r < 4; ++r) {
                    int m = m0 + i * 16 + (lane >> 4) * 4 + r;
                    int n = n0 + w * 32 + j * 16 + rb;
                    float v = (acc[i][j][r] + bias[n]) * oscale;
                    int bb = m >> 11, s = m & (SEQ - 1);
                    int hh = n >> 6, dd = n & 63;
                    size_t idx = (((size_t)(bb * 16 + hh) * SEQ) + s) * 64 + dd;
                    u16 t = f2bf(v);
                    Ch[idx] = t;
                    Cl[idx] = f2bf(v - bf2f(t));
                }
    }
}

// ---------------------------------------------------------------------------
// Output projection GEMM, 64x128 tile: 512 blocks = 2/CU co-resident.
// C = A @ W^T + bias (fp32 C). A pre-split (attn epilogue); W fp32, split
// in-register during staging.
// ---------------------------------------------------------------------------
__global__ __launch_bounds__(256)
void gemm_out(const u16* __restrict__ Ahi, const u16* __restrict__ Alo,
              const float* __restrict__ Wfp,
              const float* __restrict__ bias, float* __restrict__ C) {
    const int K = 1024, N = 1024;
    __shared__ u16 As_h[64 * 40];
    __shared__ u16 As_l[64 * 40];
    __shared__ u16 Ws_h[128 * 40];
    __shared__ u16 Ws_l[128 * 40];   // 30 KB total

    const int tid = threadIdx.x;
    const int lane = tid & 63, w = tid >> 6;     // w = wave = column slice
    const int m0 = blockIdx.y * 64, n0 = blockIdx.x * 128;
    const int rb = lane & 15, ko = (lane >> 4) * 8;

    f32x4_t acc[4][2];
    #pragma unroll
    for (int i = 0; i < 4; ++i)
        #pragma unroll
        for (int j = 0; j < 2; ++j)
            acc[i][j] = (f32x4_t){0.f, 0.f, 0.f, 0.f};

    for (int k0 = 0; k0 < K; k0 += 32) {
        {   // stage A-tile: 64 rows x 32 halves = 1 uint4/thread (pre-split)
            int r = tid >> 2, q = tid & 3;
            size_t ga = (size_t)(m0 + r) * K + k0 + q * 8;
            int la = r * 40 + q * 8;
            *(uint4*)&As_h[la] = *(const uint4*)&Ahi[ga];
            *(uint4*)&As_l[la] = *(const uint4*)&Alo[ga];
        }
        #pragma unroll
        for (int s = 0; s < 2; ++s) {   // stage W-tile (fp32 -> split)
            int c = tid + s * 256;
            int r = c >> 2, q = c & 3;
            size_t gw = (size_t)(n0 + r) * K + k0 + q * 8;
            int la = r * 40 + q * 8;
            uint4 h, l;
            splitldg(Wfp + gw, h, l);
            *(uint4*)&Ws_h[la] = h;
            *(uint4*)&Ws_l[la] = l;
        }
        __syncthreads();

        bf16x8_t ah[4], al[4];
        #pragma unroll
        for (int i = 0; i < 4; ++i) {
            int ra = i * 16 + rb;
            ah[i] = *(const bf16x8_t*)&As_h[ra * 40 + ko];
            al[i] = *(const bf16x8_t*)&As_l[ra * 40 + ko];
        }
        #pragma unroll
        for (int j = 0; j < 2; ++j) {
            int rw = w * 32 + j * 16 + rb;
            bf16x8_t wh = *(const bf16x8_t*)&Ws_h[rw * 40 + ko];
            bf16x8_t wl = *(const bf16x8_t*)&Ws_l[rw * 40 + ko];
            #pragma unroll
            for (int i = 0; i < 4; ++i) {
                acc[i][j] = __builtin_amdgcn_mfma_f32_16x16x32_bf16(ah[i], wh, acc[i][j], 0, 0, 0);
                acc[i][j] = __builtin_amdgcn_mfma_f32_16x16x32_bf16(ah[i], wl, acc[i][j], 0, 0, 0);
                acc[i][j] = __builtin_amdgcn_mfma_f32_16x16x32_bf16(al[i], wh, acc[i][j], 0, 0, 0);
            }
        }
        __syncthreads();
    }

    #pragma unroll
    for (int i = 0; i < 4; ++i)
        #pragma unroll
        for (int j = 0; j < 2; ++j)
            #pragma unroll
            for (int r = 0; r < 4; ++r) {
                int m = m0 + i * 16 + (lane >> 4) * 4 + r;
                int n = n0 + w * 32 + j * 16 + rb;
                C[(size_t)m * N + n] = acc[i][j][r] + bias[n];
            }
}

// ---------------------------------------------------------------------------
// MFMA flash attention on 32x32x16 frags, P entirely in registers.
// (r14/r29-measured 92 us structure.) Block = 4 waves x 32 q-rows.
// S^T = mfma(K, Q): q lane-local -> softmax via one shfl_xor(32); P relayout
// to PV B-operand via cvt_pk_bf16 + v_permlane32_swap. K/V in LDS (32 KB),
// XOR-swizzled; 2 barriers/tile. Fully-masked suffix handled analytically;
// the needed suffix-of-colsums is computed IN-BLOCK from cs (replaces the
// separate suffix_scan kernel). q pre-scaled by 0.125 in its projection.
// ---------------------------------------------------------------------------
__global__ __launch_bounds__(256)
void attn_mfma(const u16* __restrict__ qh_g, const u16* __restrict__ ql_g,
               const u16* __restrict__ kh_g, const u16* __restrict__ kl_g,
               const u16* __restrict__ vth_g, const u16* __restrict__ vtl_g,
               const float* __restrict__ cs,
               u16* __restrict__ ahi, u16* __restrict__ alo) {
    __shared__ alignas(16) u16 Kh[4096], Kl[4096];
    __shared__ alignas(16) u16 Vh[4096], Vl[4096];   // 32 KB total

    const int tid = threadIdx.x;
    const int lane = tid & 63, w = tid >> 6;
    const int q31 = lane & 31, g2 = lane >> 5;
    const int sidx = blockIdx.x >> 5;        // 0..15 dispatch slot
    const int stripe = (sidx < 8) ? (15 - sidx) : (sidx - 8);  // balanced pairing
    const int bh = blockIdx.x & 31;
    const int b = bh >> 4, h = bh & 15;
    const int qb0 = stripe << 7;
    const int dt_w = 2 * stripe + (w >> 1);  // this wave's diagonal tile
    const int nt_blk = 2 * stripe + 2;
    const int qrow = qb0 + w * 32 + q31;     // this lane's q (global in-head)

    // Q fragments (B-operand): col=q31, k(d) = 16*ks + 8*g2 + i
    bf16x8_t qfh[4], qfl[4];
    {
        const u16* qp = qh_g + ((size_t)bh * SEQ + qrow) * 64;
        const u16* qp2 = ql_g + ((size_t)bh * SEQ + qrow) * 64;
        #pragma unroll
        for (int ks = 0; ks < 4; ++ks) {
            qfh[ks] = *(const bf16x8_t*)(qp + ks * 16 + g2 * 8);
            qfl[ks] = *(const bf16x8_t*)(qp2 + ks * 16 + g2 * 8);
        }
    }

    f32x16_t o[2];
    #pragma unroll
    for (int dt = 0; dt < 2; ++dt)
        #pragma unroll
        for (int r = 0; r < 16; ++r) o[dt][r] = 0.f;
    float mrow = -1e30f, lrow = 0.f;

    const u16* khb = kh_g + (size_t)bh * SEQ * 64;
    const u16* klb = kl_g + (size_t)bh * SEQ * 64;
    const u16* vhb = vth_g + (size_t)bh * 64 * SEQ;
    const u16* vlb = vtl_g + (size_t)bh * 64 * SEQ;

    for (int kt = 0; kt < nt_blk; ++kt) {
        if (kt) __syncthreads();   // prior-tile LDS reads done before restage
        #pragma unroll
        for (int s = 0; s < 2; ++s) {
            int gg = tid + s * 256;          // 0..511
            int row = gg >> 3, dg = gg & 7;
            int off = row * 128 + swz(row, dg * 16);
            *(uint4*)((char*)Kh + off) = *(const uint4*)(khb + (size_t)(kt * 64 + row) * 64 + dg * 8);
            *(uint4*)((char*)Kl + off) = *(const uint4*)(klb + (size_t)(kt * 64 + row) * 64 + dg * 8);
            *(uint4*)((char*)Vh + off) = *(const uint4*)(vhb + (size_t)row * SEQ + kt * 64 + dg * 8);
            *(uint4*)((char*)Vl + off) = *(const uint4*)(vlb + (size_t)row * SEQ + kt * 64 + dg * 8);
        }
        __syncthreads();           // staging visible
        if (kt > dt_w) continue;   // wave-uniform; barriers stay aligned

        // ---- QK^T: st[jt] = S^T frag (rows j, cols q) ----
        f32x16_t st[2];
        #pragma unroll
        for (int jt = 0; jt < 2; ++jt)
            #pragma unroll
            for (int r = 0; r < 16; ++r) st[jt][r] = 0.f;
        #pragma unroll
        for (int ks = 0; ks < 4; ++ks)
            #pragma unroll
            for (int jt = 0; jt < 2; ++jt) {
                int row = jt * 32 + q31;
                int off = row * 128 + swz(row, ks * 32 + g2 * 16);
                bf16x8_t kh8 = *(const bf16x8_t*)((char*)Kh + off);
                bf16x8_t kl8 = *(const bf16x8_t*)((char*)Kl + off);
                st[jt] = __builtin_amdgcn_mfma_f32_32x32x16_bf16(kh8, qfh[ks], st[jt], 0, 0, 0);
                st[jt] = __builtin_amdgcn_mfma_f32_32x32x16_bf16(kh8, qfl[ks], st[jt], 0, 0, 0);
                st[jt] = __builtin_amdgcn_mfma_f32_32x32x16_bf16(kl8, qfh[ks], st[jt], 0, 0, 0);
            }

        // causal mask on the diagonal tile (reference semantics: -1e-9)
        if (kt == dt_w) {
            #pragma unroll
            for (int jt = 0; jt < 2; ++jt)
                #pragma unroll
                for (int r = 0; r < 16; ++r) {
                    int j = kt * 64 + jt * 32 + (r & 3) + 8 * (r >> 2) + 4 * g2;
                    if (j > qrow) st[jt][r] = -1e-9f;
                }
        }

        // ---- online softmax: q is lane-local; partner lane^32 has the
        //      complementary j-subset -> one shfl_xor each for max & sum ----
        float mx = -1e30f;
        #pragma unroll
        for (int jt = 0; jt < 2; ++jt)
            #pragma unroll
            for (int r = 0; r < 16; ++r) mx = fmaxf(mx, st[jt][r]);
        mx = fmaxf(mx, __shfl_xor(mx, 32));
        float nm = fmaxf(mrow, mx);
        float alpha = __expf(mrow - nm);
        mrow = nm;
        float rs = 0.f;
        #pragma unroll
        for (int jt = 0; jt < 2; ++jt)
            #pragma unroll
            for (int r = 0; r < 16; ++r) {
                float p = __expf(st[jt][r] - nm);
                st[jt][r] = p;
                rs += p;
            }
        rs += __shfl_xor(rs, 32);
        lrow = lrow * alpha + rs;
        #pragma unroll
        for (int dt = 0; dt < 2; ++dt)
            #pragma unroll
            for (int r = 0; r < 16; ++r) o[dt][r] *= alpha;

        // ---- pack P to PV B-frags in-register (cvt_pk + permlane32_swap) ----
        bf16x8_t pbh[4], pbl[4];
        #pragma unroll
        for (int jt = 0; jt < 2; ++jt) {
            u32 hq[8], lq[8];
            #pragma unroll
            for (int p2 = 0; p2 < 8; ++p2) {
                float s0 = st[jt][p2 * 2], s1 = st[jt][p2 * 2 + 1];
                u32 hk = cvtpk(s0, s1);
                hq[p2] = hk;
                float l0 = s0 - __uint_as_float(hk << 16);
                float l1 = s1 - __uint_as_float(hk & 0xFFFF0000u);
                lq[p2] = cvtpk(l0, l1);
            }
            // halves: r0-7 -> ks=2jt, r8-15 -> ks=2jt+1
            plswap(hq[0], hq[2]); plswap(hq[1], hq[3]);
            plswap(hq[4], hq[6]); plswap(hq[5], hq[7]);
            plswap(lq[0], lq[2]); plswap(lq[1], lq[3]);
            plswap(lq[4], lq[6]); plswap(lq[5], lq[7]);
            uint4 t;
            t = (uint4){hq[0], hq[1], hq[2], hq[3]};
            pbh[2 * jt] = *(bf16x8_t*)&t;
            t = (uint4){hq[4], hq[5], hq[6], hq[7]};
            pbh[2 * jt + 1] = *(bf16x8_t*)&t;
            t = (uint4){lq[0], lq[1], lq[2], lq[3]};
            pbl[2 * jt] = *(bf16x8_t*)&t;
            t = (uint4){lq[4], lq[5], lq[6], lq[7]};
            pbl[2 * jt + 1] = *(bf16x8_t*)&t;
        }

        // ---- PV: O^T[dt] += V^T frag x P frag ----
        #pragma unroll
        for (int ks = 0; ks < 4; ++ks)
            #pragma unroll
            for (int dt = 0; dt < 2; ++dt) {
                int row = dt * 32 + q31;
                int off = row * 128 + swz(row, ks * 32 + g2 * 16);
                bf16x8_t vh8 = *(const bf16x8_t*)((char*)Vh + off);
                bf16x8_t vl8 = *(const bf16x8_t*)((char*)Vl + off);
                o[dt] = __builtin_amdgcn_mfma_f32_32x32x16_bf16(vh8, pbh[ks], o[dt], 0, 0, 0);
                o[dt] = __builtin_amdgcn_mfma_f32_32x32x16_bf16(vh8, pbl[ks], o[dt], 0, 0, 0);
                o[dt] = __builtin_amdgcn_mfma_f32_32x32x16_bf16(vl8, pbh[ks], o[dt], 0, 0, 0);
            }
    }

    // ---- in-block suffix-of-colsums (replaces suffix_scan kernel) ----
    // Shared part S2[d] = sum_{kt >= 2*stripe+2} cs[bh][kt][d]; waves 0,1
    // (diag one tile earlier) additionally add cs[bh][2*stripe+1][d].
    __syncthreads();                          // all waves done with K/V LDS
    float* sred = (float*)Kh;                 // reuse dead K region (8 KB)
    const int base_t = 2 * stripe + 2;
    {
        int d = tid & 63, grp = tid >> 6;     // 4 strided partial groups
        float s = 0.f;
        for (int t2 = base_t + grp; t2 < NKT; t2 += 4)
            s += cs[((size_t)bh * NKT + t2) * 64 + d];
        sred[grp * 64 + d] = s;
    }
    __syncthreads();
    if (tid < 64)
        sred[256 + tid] = (sred[tid] + sred[64 + tid]) +
                          (sred[128 + tid] + sred[192 + tid]);
    __syncthreads();

    // fully-masked suffix tiles: analytic e * suffix-colsum(V)
    const int nt_w = dt_w + 1;
    const int nfull = NKT - nt_w;
    if (nfull > 0) {
        float mm = fmaxf(mrow, -1e-9f);
        float al2 = __expf(mrow - mm);
        float ee = __expf(-1e-9f - mm);
        lrow = lrow * al2 + ee * (64.f * (float)nfull);
        const bool extra = (nt_w < base_t);   // waves 0,1: add one more tile
        const float* csrow = cs + ((size_t)bh * NKT + nt_w) * 64;
        #pragma unroll
        for (int dt = 0; dt < 2; ++dt)
            #pragma unroll
            for (int qq = 0; qq < 4; ++qq) {
                int d0 = dt * 32 + qq * 8 + g2 * 4;
                float4 sf = *(const float4*)&sred[256 + d0];
                if (extra) {
                    float4 c4 = *(const float4*)(csrow + d0);
                    sf.x += c4.x; sf.y += c4.y; sf.z += c4.z; sf.w += c4.w;
                }
                o[dt][qq * 4 + 0] = o[dt][qq * 4 + 0] * al2 + ee * sf.x;
                o[dt][qq * 4 + 1] = o[dt][qq * 4 + 1] * al2 + ee * sf.y;
                o[dt][qq * 4 + 2] = o[dt][qq * 4 + 2] * al2 + ee * sf.z;
                o[dt][qq * 4 + 3] = o[dt][qq * 4 + 3] * al2 + ee * sf.w;
            }
    }

    // epilogue: normalize + write bf16 hi/lo in [B*S][DMODEL]
    float inv = 1.f / lrow;
    size_t rowg = (size_t)b * SEQ + qrow;
    #pragma unroll
    for (int dt = 0; dt < 2; ++dt)
        #pragma unroll
        for (int qq = 0; qq < 4; ++qq) {
            int d0 = dt * 32 + qq * 8 + g2 * 4;
            ushort4 h4, l4;
            float v0 = o[dt][qq * 4 + 0] * inv;
            float v1 = o[dt][qq * 4 + 1] * inv;
            float v2 = o[dt][qq * 4 + 2] * inv;
            float v3 = o[dt][qq * 4 + 3] * inv;
            h4.x = f2bf(v0); l4.x = f2bf(v0 - bf2f(h4.x));
            h4.y = f2bf(v1); l4.y = f2bf(v1 - bf2f(h4.y));
            h4.z = f2bf(v2); l4.z = f2bf(v2 - bf2f(h4.z));
            h4.w = f2bf(v3); l4.w = f2bf(v3 - bf2f(h4.w));
            size_t col = (size_t)h * 64 + d0;
            *(ushort4*)&ahi[rowg * DMODEL + col] = h4;
            *(ushort4*)&alo[rowg * DMODEL + col] = l4;
        }
}

// ---------------------------------------------------------------------------
extern "C" void kernel_launch(void* const* d_in, const int* in_sizes, int n_in,
                              void* d_out, int out_size, void* d_ws, size_t ws_size,
                              hipStream_t stream) {
    const float* Q   = (const float*)d_in[0];
    const float* K   = (const float*)d_in[1];
    const float* V   = (const float*)d_in[2];
    // d_in[3] = mask (tril) — structure known, not read
    const float* Wq  = (const float*)d_in[4];
    const float* bq  = (const float*)d_in[5];
    const float* Wk  = (const float*)d_in[6];
    const float* bk  = (const float*)d_in[7];
    const float* Wv  = (const float*)d_in[8];
    const float* bv  = (const float*)d_in[9];
    const float* Wo  = (const float*)d_in[10];
    const float* bo  = (const float*)d_in[11];
    float* out = (float*)d_out;

    float* ws = (float*)d_ws;
    const size_t HEADSZ = (size_t)BHTOT * SEQ * HDIM;   // 4,194,304 elems
    float* cs_ws  = ws;                                  // 65536 f
    u16* base  = (u16*)(ws + 131072);
    u16* q_hi  = base;
    u16* q_lo  = base + HEADSZ;
    u16* k_hi  = base + 2 * HEADSZ;
    u16* k_lo  = base + 3 * HEADSZ;
    u16* vt_hi = base + 4 * HEADSZ;
    u16* vt_lo = base + 5 * HEADSZ;
    u16* in_hi = base + 6 * HEADSZ;   // attn output splits (O-GEMM input)
    u16* in_lo = base + 7 * HEADSZ;

    dim3 gblk(256);
    dim3 gout(DMODEL / 128, MROWS / 64);                 // 8 x 64 = 512 blocks
    dim3 gqkv(DMODEL / 128, MROWS / 64, 3);              // 8 x 64 x 3 = 1536 blocks

    // fused Q/K/V projections (A+W split in-staging; V colsums fused)
    gemm_qkv<<<gqkv, gblk, 0, stream>>>(Q, K, V, Wq, Wk, Wv, bq, bk, bv,
                                        q_hi, q_lo, k_hi, k_lo, vt_hi, vt_lo,
                                        cs_ws);

    // MFMA flash attention (suffix-of-colsums computed in-block from cs)
    attn_mfma<<<dim3(16 * BHTOT), gblk, 0, stream>>>(q_hi, q_lo, k_hi, k_lo,
                                                     vt_hi, vt_lo, cs_ws,
                                                     in_hi, in_lo);

    // output projection (64x128 tiles, 512 blocks = 2/CU; W split in-staging)
    gemm_out<<<gout, gblk, 0, stream>>>(in_hi, in_lo, Wo, bo, out);
}